// Round 1
// baseline (1508.130 us; speedup 1.0000x reference)
//
#include <hip/hip_runtime.h>

#define N_NODES 50000
#define N_EDGES 800000
#define D_EDGE 64
#define D_NODE 64
#define D_IN 192
#define D_HID 256
#define D_OUT 64

// ---------------------------------------------------------------------------
// Kernel 1: scatter-add edge features into in_agg (by receiver) and out_agg
// (by sender). One thread per (edge, 4-float chunk): coalesced float4 read,
// 8 scalar float atomics into L2.
// ---------------------------------------------------------------------------
__global__ __launch_bounds__(256) void scatter_kernel(
    const float* __restrict__ edge_feat,
    const int* __restrict__ senders,
    const int* __restrict__ receivers,
    float* __restrict__ in_agg,
    float* __restrict__ out_agg) {
    int t = blockIdx.x * blockDim.x + threadIdx.x;
    const int total = N_EDGES * (D_EDGE / 4);
    if (t >= total) return;
    int edge = t >> 4;          // D_EDGE/4 == 16 chunks per edge
    int c = (t & 15) * 4;
    const float4 v = *reinterpret_cast<const float4*>(edge_feat + (size_t)edge * D_EDGE + c);
    int r = receivers[edge];
    int s = senders[edge];
    float* pin = in_agg + (size_t)r * D_EDGE + c;
    float* pou = out_agg + (size_t)s * D_EDGE + c;
    atomicAdd(pin + 0, v.x);
    atomicAdd(pin + 1, v.y);
    atomicAdd(pin + 2, v.z);
    atomicAdd(pin + 3, v.w);
    atomicAdd(pou + 0, v.x);
    atomicAdd(pou + 1, v.y);
    atomicAdd(pou + 2, v.z);
    atomicAdd(pou + 3, v.w);
}

// ---------------------------------------------------------------------------
// Kernel 2: fused 2-layer MLP.  16 nodes per block, 256 threads.
// Phase A: stage x = [in_agg | out_agg | node_feat]  (16 x 192) in LDS.
// Phase B: thread t computes hidden unit t for all 16 nodes (W1 column in a
//          register per k; x broadcast-read from LDS -> no bank conflicts).
// Phase C: thread computes 4 outputs (col = tid&63, 4 consecutive nodes);
//          h broadcast-read from LDS.
// ---------------------------------------------------------------------------
__global__ __launch_bounds__(256) void mlp_kernel(
    const float* __restrict__ in_agg,
    const float* __restrict__ out_agg,
    const float* __restrict__ node_feat,
    const float* __restrict__ W1,   // [192][256]
    const float* __restrict__ b1,   // [256]
    const float* __restrict__ W2,   // [256][64]
    const float* __restrict__ b2,   // [64]
    float* __restrict__ out) {      // [N][64]
    __shared__ float x_tile[16][D_IN];    // 12 KB
    __shared__ float h_tile[16][D_HID];   // 16 KB
    const int node0 = blockIdx.x * 16;
    const int tid = threadIdx.x;

    // Phase A: load x tile
    for (int i = tid; i < 16 * D_IN; i += 256) {
        int n = i / D_IN;
        int k = i - n * D_IN;
        int node = node0 + n;
        float v = 0.f;
        if (node < N_NODES) {
            if (k < D_EDGE) {
                v = in_agg[(size_t)node * D_EDGE + k];
            } else if (k < 2 * D_EDGE) {
                v = out_agg[(size_t)node * D_EDGE + (k - D_EDGE)];
            } else {
                v = node_feat[(size_t)node * D_NODE + (k - 2 * D_EDGE)];
            }
        }
        x_tile[n][k] = v;
    }
    __syncthreads();

    // Phase B: hidden layer. thread t owns hidden unit t for all 16 nodes.
    {
        float acc[16];
        float bias = b1[tid];
#pragma unroll
        for (int n = 0; n < 16; n++) acc[n] = bias;
        for (int k = 0; k < D_IN; k++) {
            float w = W1[(size_t)k * D_HID + tid];
#pragma unroll
            for (int n = 0; n < 16; n++) acc[n] = fmaf(x_tile[n][k], w, acc[n]);
        }
#pragma unroll
        for (int n = 0; n < 16; n++) h_tile[n][tid] = fmaxf(acc[n], 0.f);
    }
    __syncthreads();

    // Phase C: output layer. thread -> (col = tid&63, nodes n0..n0+3).
    {
        const int c = tid & 63;
        const int n0 = (tid >> 6) * 4;
        float acc[4];
        float bias = b2[c];
#pragma unroll
        for (int j = 0; j < 4; j++) acc[j] = bias;
        for (int k = 0; k < D_HID; k++) {
            float w = W2[(size_t)k * D_OUT + c];
#pragma unroll
            for (int j = 0; j < 4; j++) acc[j] = fmaf(h_tile[n0 + j][k], w, acc[j]);
        }
#pragma unroll
        for (int j = 0; j < 4; j++) {
            int node = node0 + n0 + j;
            if (node < N_NODES) out[(size_t)node * D_OUT + c] = acc[j];
        }
    }
}

extern "C" void kernel_launch(void* const* d_in, const int* in_sizes, int n_in,
                              void* d_out, int out_size, void* d_ws, size_t ws_size,
                              hipStream_t stream) {
    const float* node_feat = (const float*)d_in[0];
    const float* edge_feat = (const float*)d_in[1];
    const int* senders     = (const int*)d_in[2];
    const int* receivers   = (const int*)d_in[3];
    const float* W1        = (const float*)d_in[4];
    const float* b1        = (const float*)d_in[5];
    const float* W2        = (const float*)d_in[6];
    const float* b2        = (const float*)d_in[7];
    float* out = (float*)d_out;

    float* in_agg  = (float*)d_ws;
    float* out_agg = in_agg + (size_t)N_NODES * D_EDGE;

    // zero the aggregation buffers (poisoned 0xAA otherwise; not re-zeroed
    // between replays, so we must do it ourselves every call)
    hipMemsetAsync(d_ws, 0, (size_t)2 * N_NODES * D_EDGE * sizeof(float), stream);

    {
        const int total = N_EDGES * (D_EDGE / 4);
        dim3 grid((total + 255) / 256), block(256);
        scatter_kernel<<<grid, block, 0, stream>>>(edge_feat, senders, receivers,
                                                   in_agg, out_agg);
    }
    {
        dim3 grid((N_NODES + 15) / 16), block(256);
        mlp_kernel<<<grid, block, 0, stream>>>(in_agg, out_agg, node_feat,
                                               W1, b1, W2, b2, out);
    }
}

// Round 2
// 701.708 us; speedup vs baseline: 2.1492x; 2.1492x over previous
//
#include <hip/hip_runtime.h>

#define N_NODES 50000
#define N_EDGES 800000
#define D_EDGE 64
#define D_NODE 64
#define D_IN 192
#define D_HID 256
#define D_OUT 64

// ---------------------------------------------------------------------------
// K1: histogram — count in-degree (by receiver) and out-degree (by sender).
// Int atomics on 200 KB arrays (L2-resident).
// ---------------------------------------------------------------------------
__global__ __launch_bounds__(256) void hist_kernel(
    const int* __restrict__ senders,
    const int* __restrict__ receivers,
    int* __restrict__ cnt_in,
    int* __restrict__ cnt_out) {
    int e = blockIdx.x * blockDim.x + threadIdx.x;
    if (e < N_EDGES) {
        atomicAdd(&cnt_in[receivers[e]], 1);
        atomicAdd(&cnt_out[senders[e]], 1);
    }
}

// ---------------------------------------------------------------------------
// K2: exclusive prefix scan of the two count arrays (one block each,
// grid.x = 2). Writes offs[] (50001 entries) and a working copy cur[].
// ---------------------------------------------------------------------------
__global__ __launch_bounds__(1024) void scan_kernel(
    const int* __restrict__ cnt_in,  int* __restrict__ offs_in,  int* __restrict__ cur_in,
    const int* __restrict__ cnt_out, int* __restrict__ offs_out, int* __restrict__ cur_out) {
    const int* cnt; int* offs; int* cur;
    if (blockIdx.x == 0) { cnt = cnt_in;  offs = offs_in;  cur = cur_in; }
    else                 { cnt = cnt_out; offs = offs_out; cur = cur_out; }

    __shared__ int sums[1024];
    const int CH = (N_NODES + 1023) / 1024;   // 49 elements per thread
    const int t = threadIdx.x;
    const int base = t * CH;

    int s = 0;
    for (int i = 0; i < CH; i++) {
        int idx = base + i;
        if (idx < N_NODES) s += cnt[idx];
    }
    sums[t] = s;
    __syncthreads();
    // Hillis-Steele inclusive scan over 1024 thread-sums
    for (int off = 1; off < 1024; off <<= 1) {
        int v = (t >= off) ? sums[t - off] : 0;
        __syncthreads();
        sums[t] += v;
        __syncthreads();
    }
    int run = sums[t] - s;   // exclusive prefix for this thread's chunk
    for (int i = 0; i < CH; i++) {
        int idx = base + i;
        if (idx < N_NODES) {
            offs[idx] = run;
            cur[idx] = run;
            run += cnt[idx];
        }
    }
    if (t == 1023) offs[N_NODES] = sums[1023];
}

// ---------------------------------------------------------------------------
// K3: fill — scatter edge ids into CSR index lists using atomic cursors.
// ---------------------------------------------------------------------------
__global__ __launch_bounds__(256) void fill_kernel(
    const int* __restrict__ senders,
    const int* __restrict__ receivers,
    int* __restrict__ cur_in,
    int* __restrict__ cur_out,
    int* __restrict__ in_idx,
    int* __restrict__ out_idx) {
    int e = blockIdx.x * blockDim.x + threadIdx.x;
    if (e < N_EDGES) {
        int p = atomicAdd(&cur_in[receivers[e]], 1);
        in_idx[p] = e;
        int q = atomicAdd(&cur_out[senders[e]], 1);
        out_idx[q] = e;
    }
}

// ---------------------------------------------------------------------------
// K4: fused gather + 2-layer MLP. 16 nodes / block, 256 threads (4 waves).
// Phase A: each wave gathers 4 nodes' in/out edge sums (lane = feature col;
//          each edge row read is 64 lanes x 4 B = 256 B coalesced).
// Phase B: thread t computes hidden unit t for all 16 nodes (x broadcast
//          from LDS, W1 column coalesced from L2).
// Phase C: thread -> (out col = tid&63, 4 nodes); h broadcast from LDS.
// ---------------------------------------------------------------------------
__global__ __launch_bounds__(256) void fused_mlp_kernel(
    const float* __restrict__ edge_feat,
    const float* __restrict__ node_feat,
    const int* __restrict__ offs_in,
    const int* __restrict__ in_idx,
    const int* __restrict__ offs_out,
    const int* __restrict__ out_idx,
    const float* __restrict__ W1,   // [192][256]
    const float* __restrict__ b1,   // [256]
    const float* __restrict__ W2,   // [256][64]
    const float* __restrict__ b2,   // [64]
    float* __restrict__ out) {      // [N][64]
    __shared__ float x_tile[16][D_IN];    // 12 KB
    __shared__ float h_tile[16][D_HID];   // 16 KB
    const int node0 = blockIdx.x * 16;
    const int tid = threadIdx.x;
    const int wave = tid >> 6;
    const int lane = tid & 63;

    // Phase A: gather. wave w handles nodes w*4 .. w*4+3 of the tile.
#pragma unroll
    for (int j = 0; j < 4; j++) {
        const int n = wave * 4 + j;
        const int node = node0 + n;
        float acc_in = 0.f, acc_out = 0.f, nf = 0.f;
        if (node < N_NODES) {
            int b = offs_in[node], e = offs_in[node + 1];
            for (int i = b; i < e; i++) {
                int ed = in_idx[i];
                acc_in += edge_feat[(size_t)ed * D_EDGE + lane];
            }
            b = offs_out[node]; e = offs_out[node + 1];
            for (int i = b; i < e; i++) {
                int ed = out_idx[i];
                acc_out += edge_feat[(size_t)ed * D_EDGE + lane];
            }
            nf = node_feat[(size_t)node * D_NODE + lane];
        }
        x_tile[n][lane] = acc_in;
        x_tile[n][D_EDGE + lane] = acc_out;
        x_tile[n][2 * D_EDGE + lane] = nf;
    }
    __syncthreads();

    // Phase B: hidden layer
    {
        float acc[16];
        float bias = b1[tid];
#pragma unroll
        for (int n = 0; n < 16; n++) acc[n] = bias;
        for (int k = 0; k < D_IN; k++) {
            float w = W1[(size_t)k * D_HID + tid];
#pragma unroll
            for (int n = 0; n < 16; n++) acc[n] = fmaf(x_tile[n][k], w, acc[n]);
        }
#pragma unroll
        for (int n = 0; n < 16; n++) h_tile[n][tid] = fmaxf(acc[n], 0.f);
    }
    __syncthreads();

    // Phase C: output layer
    {
        const int c = tid & 63;
        const int n0 = (tid >> 6) * 4;
        float acc[4];
        float bias = b2[c];
#pragma unroll
        for (int j = 0; j < 4; j++) acc[j] = bias;
        for (int k = 0; k < D_HID; k++) {
            float w = W2[(size_t)k * D_OUT + c];
#pragma unroll
            for (int j = 0; j < 4; j++) acc[j] = fmaf(h_tile[n0 + j][k], w, acc[j]);
        }
#pragma unroll
        for (int j = 0; j < 4; j++) {
            int node = node0 + n0 + j;
            if (node < N_NODES) out[(size_t)node * D_OUT + c] = acc[j];
        }
    }
}

extern "C" void kernel_launch(void* const* d_in, const int* in_sizes, int n_in,
                              void* d_out, int out_size, void* d_ws, size_t ws_size,
                              hipStream_t stream) {
    const float* node_feat = (const float*)d_in[0];
    const float* edge_feat = (const float*)d_in[1];
    const int* senders     = (const int*)d_in[2];
    const int* receivers   = (const int*)d_in[3];
    const float* W1        = (const float*)d_in[4];
    const float* b1        = (const float*)d_in[5];
    const float* W2        = (const float*)d_in[6];
    const float* b2        = (const float*)d_in[7];
    float* out = (float*)d_out;

    // workspace layout (ints)
    int* ws = (int*)d_ws;
    int* cnt_in   = ws;                      // 50000
    int* cnt_out  = cnt_in + N_NODES;        // 50000
    int* offs_in  = cnt_out + N_NODES;       // 50001
    int* offs_out = offs_in + (N_NODES + 1); // 50001
    int* cur_in   = offs_out + (N_NODES + 1);// 50001
    int* cur_out  = cur_in + (N_NODES + 1);  // 50001
    int* in_idx   = cur_out + (N_NODES + 1); // 800000
    int* out_idx  = in_idx + N_EDGES;        // 800000

    // zero only the count arrays (everything else is fully overwritten)
    hipMemsetAsync(cnt_in, 0, (size_t)2 * N_NODES * sizeof(int), stream);

    {
        dim3 grid((N_EDGES + 255) / 256), block(256);
        hist_kernel<<<grid, block, 0, stream>>>(senders, receivers, cnt_in, cnt_out);
    }
    {
        scan_kernel<<<dim3(2), dim3(1024), 0, stream>>>(cnt_in, offs_in, cur_in,
                                                        cnt_out, offs_out, cur_out);
    }
    {
        dim3 grid((N_EDGES + 255) / 256), block(256);
        fill_kernel<<<grid, block, 0, stream>>>(senders, receivers, cur_in, cur_out,
                                                in_idx, out_idx);
    }
    {
        dim3 grid((N_NODES + 15) / 16), block(256);
        fused_mlp_kernel<<<grid, block, 0, stream>>>(edge_feat, node_feat,
                                                     offs_in, in_idx, offs_out, out_idx,
                                                     W1, b1, W2, b2, out);
    }
}

// Round 3
// 418.875 us; speedup vs baseline: 3.6004x; 1.6752x over previous
//
#include <hip/hip_runtime.h>

#define N_NODES 50000
#define N_EDGES 800000
#define D_EDGE 64
#define D_NODE 64
#define D_IN 192
#define D_HID 256
#define D_OUT 64

typedef __attribute__((ext_vector_type(8))) short bf16x8;
typedef __attribute__((ext_vector_type(4))) float f32x4;

__device__ inline ushort f2bf(float f) {
    union { float f; unsigned u; } v; v.f = f;
    unsigned r = v.u + 0x7fff + ((v.u >> 16) & 1);   // round-to-nearest-even
    return (ushort)(r >> 16);
}

// ---------------------------------------------------------------------------
// K1: histogram of in-degree (receiver) / out-degree (sender)
// ---------------------------------------------------------------------------
__global__ __launch_bounds__(256) void hist_kernel(
    const int* __restrict__ senders, const int* __restrict__ receivers,
    int* __restrict__ cnt_in, int* __restrict__ cnt_out) {
    int e = blockIdx.x * blockDim.x + threadIdx.x;
    if (e < N_EDGES) {
        atomicAdd(&cnt_in[receivers[e]], 1);
        atomicAdd(&cnt_out[senders[e]], 1);
    }
}

// ---------------------------------------------------------------------------
// K2: exclusive prefix scan (one block per array, grid.x = 2)
// ---------------------------------------------------------------------------
__global__ __launch_bounds__(1024) void scan_kernel(
    const int* __restrict__ cnt_in,  int* __restrict__ offs_in,  int* __restrict__ cur_in,
    const int* __restrict__ cnt_out, int* __restrict__ offs_out, int* __restrict__ cur_out) {
    const int* cnt; int* offs; int* cur;
    if (blockIdx.x == 0) { cnt = cnt_in;  offs = offs_in;  cur = cur_in; }
    else                 { cnt = cnt_out; offs = offs_out; cur = cur_out; }
    __shared__ int sums[1024];
    const int CH = (N_NODES + 1023) / 1024;
    const int t = threadIdx.x;
    const int base = t * CH;
    int s = 0;
    for (int i = 0; i < CH; i++) { int idx = base + i; if (idx < N_NODES) s += cnt[idx]; }
    sums[t] = s;
    __syncthreads();
    for (int off = 1; off < 1024; off <<= 1) {
        int v = (t >= off) ? sums[t - off] : 0;
        __syncthreads();
        sums[t] += v;
        __syncthreads();
    }
    int run = sums[t] - s;
    for (int i = 0; i < CH; i++) {
        int idx = base + i;
        if (idx < N_NODES) { offs[idx] = run; cur[idx] = run; run += cnt[idx]; }
    }
    if (t == 1023) offs[N_NODES] = sums[1023];
}

// ---------------------------------------------------------------------------
// K3: fill CSR edge-id lists via atomic cursors
// ---------------------------------------------------------------------------
__global__ __launch_bounds__(256) void fill_kernel(
    const int* __restrict__ senders, const int* __restrict__ receivers,
    int* __restrict__ cur_in, int* __restrict__ cur_out,
    int* __restrict__ in_idx, int* __restrict__ out_idx) {
    int e = blockIdx.x * blockDim.x + threadIdx.x;
    if (e < N_EDGES) {
        int p = atomicAdd(&cur_in[receivers[e]], 1);
        in_idx[p] = e;
        int q = atomicAdd(&cur_out[senders[e]], 1);
        out_idx[q] = e;
    }
}

// ---------------------------------------------------------------------------
// K4: gather — one wave per (node, side). lane = feature col.
// 4-way unrolled independent row loads; writes bf16 x[node][side*64+lane].
// ---------------------------------------------------------------------------
__global__ __launch_bounds__(256) void gather_kernel(
    const float* __restrict__ edge_feat,
    const int* __restrict__ offs_in,  const int* __restrict__ in_idx,
    const int* __restrict__ offs_out, const int* __restrict__ out_idx,
    ushort* __restrict__ x) {          // [N_NODES][128] bf16
    int task = blockIdx.x * 4 + (threadIdx.x >> 6);
    if (task >= 2 * N_NODES) return;
    const int lane = threadIdx.x & 63;
    const int node = task >> 1;
    const int side = task & 1;
    const int* offs = side ? offs_out : offs_in;
    const int* idx  = side ? out_idx  : in_idx;
    int b = offs[node], e = offs[node + 1];
    float acc = 0.f;
    int i = b;
    for (; i + 4 <= e; i += 4) {
        int e0 = idx[i], e1 = idx[i + 1], e2 = idx[i + 2], e3 = idx[i + 3];
        float v0 = edge_feat[(size_t)e0 * D_EDGE + lane];
        float v1 = edge_feat[(size_t)e1 * D_EDGE + lane];
        float v2 = edge_feat[(size_t)e2 * D_EDGE + lane];
        float v3 = edge_feat[(size_t)e3 * D_EDGE + lane];
        acc += v0 + v1 + v2 + v3;
    }
    for (; i < e; i++) acc += edge_feat[(size_t)idx[i] * D_EDGE + lane];
    x[(size_t)node * 128 + side * 64 + lane] = f2bf(acc);
}

// ---------------------------------------------------------------------------
// K5: pack W1/W2 (f32) into bf16 fragment-major layout for MFMA B-operands.
// W1: 16 ntiles x 6 ksteps x 64 lanes x 8 elems; W2: 4 x 8 x 64 x 8.
// lane l (g=l>>4, c=l&15), elem j  ->  W[k = s*32+g*8+j][n = nt*16+c]
// ---------------------------------------------------------------------------
__global__ __launch_bounds__(256) void pack_w_kernel(
    const float* __restrict__ W1, const float* __restrict__ W2,
    ushort* __restrict__ w1p, ushort* __restrict__ w2p) {
    int idx = blockIdx.x * 256 + threadIdx.x;   // 8192 total
    if (idx < 6144) {
        int nt = idx / 384, rem = idx % 384;
        int s = rem / 64, l = rem % 64;
        int g = l >> 4, c = l & 15;
        ushort* dst = w1p + (size_t)idx * 8;
#pragma unroll
        for (int j = 0; j < 8; j++) {
            int k = s * 32 + g * 8 + j;
            dst[j] = f2bf(W1[(size_t)k * D_HID + nt * 16 + c]);
        }
    } else if (idx < 8192) {
        int id2 = idx - 6144;
        int nt = id2 / 512, rem = id2 % 512;
        int s = rem / 64, l = rem % 64;
        int g = l >> 4, c = l & 15;
        ushort* dst = w2p + (size_t)id2 * 8;
#pragma unroll
        for (int j = 0; j < 8; j++) {
            int k = s * 32 + g * 8 + j;
            dst[j] = f2bf(W2[(size_t)k * D_OUT + nt * 16 + c]);
        }
    }
}

// ---------------------------------------------------------------------------
// K6: MFMA MLP. Block = 256 thr (4 waves), 32 nodes (2 mtiles).
// L1: M=32,N=256,K=192 (ksteps 0..3 from bf16 x; 4..5 from f32 node_feat).
// wave w owns ntiles {w, w+4, w+8, w+12}. H -> LDS (pad 8). L2: K=256,N=64.
// ---------------------------------------------------------------------------
__global__ __launch_bounds__(256) void mlp_mfma_kernel(
    const ushort* __restrict__ x,        // [N][128] bf16
    const float* __restrict__ node_feat, // [N][64]
    const ushort* __restrict__ w1p, const float* __restrict__ b1,
    const ushort* __restrict__ w2p, const float* __restrict__ b2,
    float* __restrict__ out) {
    __shared__ ushort h_lds[32][D_HID + 8];   // stride 264*2=528 B
    const int tid = threadIdx.x;
    const int wave = tid >> 6, lane = tid & 63;
    const int g = lane >> 4, c = lane & 15;
    const int node0 = blockIdx.x * 32;

    f32x4 acc[2][4];
#pragma unroll
    for (int m = 0; m < 2; m++)
#pragma unroll
        for (int q = 0; q < 4; q++) acc[m][q] = (f32x4){0.f, 0.f, 0.f, 0.f};

    const bf16x8* w1v = (const bf16x8*)w1p;
    const bf16x8* w2v = (const bf16x8*)w2p;

    // rows this thread's A-fragments come from (clamped; extra rows discarded)
    int row0 = node0 + c;            if (row0 > N_NODES - 1) row0 = N_NODES - 1;
    int row1 = node0 + 16 + c;       if (row1 > N_NODES - 1) row1 = N_NODES - 1;

#pragma unroll
    for (int s = 0; s < 6; s++) {
        bf16x8 a0, a1;
        if (s < 4) {
            a0 = *(const bf16x8*)(x + (size_t)row0 * 128 + s * 32 + g * 8);
            a1 = *(const bf16x8*)(x + (size_t)row1 * 128 + s * 32 + g * 8);
        } else {
            const float* p0 = node_feat + (size_t)row0 * D_NODE + (s - 4) * 32 + g * 8;
            const float* p1 = node_feat + (size_t)row1 * D_NODE + (s - 4) * 32 + g * 8;
            union { bf16x8 v; ushort u[8]; } t0, t1;
#pragma unroll
            for (int j = 0; j < 8; j++) { t0.u[j] = f2bf(p0[j]); t1.u[j] = f2bf(p1[j]); }
            a0 = t0.v; a1 = t1.v;
        }
#pragma unroll
        for (int q = 0; q < 4; q++) {
            int nt = wave + q * 4;
            bf16x8 b = w1v[(nt * 6 + s) * 64 + lane];
            acc[0][q] = __builtin_amdgcn_mfma_f32_16x16x32_bf16(a0, b, acc[0][q], 0, 0, 0);
            acc[1][q] = __builtin_amdgcn_mfma_f32_16x16x32_bf16(a1, b, acc[1][q], 0, 0, 0);
        }
    }

    // bias + relu -> h_lds (bf16)
#pragma unroll
    for (int q = 0; q < 4; q++) {
        int nt = wave + q * 4;
        float bv = b1[nt * 16 + c];
#pragma unroll
        for (int mt = 0; mt < 2; mt++)
#pragma unroll
            for (int r = 0; r < 4; r++) {
                int row = mt * 16 + g * 4 + r;
                h_lds[row][nt * 16 + c] = f2bf(fmaxf(acc[mt][q][r] + bv, 0.f));
            }
    }
    __syncthreads();

    // layer 2: ntile = wave (N=64)
    f32x4 acc2[2];
    acc2[0] = (f32x4){0.f, 0.f, 0.f, 0.f};
    acc2[1] = (f32x4){0.f, 0.f, 0.f, 0.f};
#pragma unroll
    for (int s = 0; s < 8; s++) {
        bf16x8 b = w2v[(wave * 8 + s) * 64 + lane];
#pragma unroll
        for (int mt = 0; mt < 2; mt++) {
            bf16x8 a = *(const bf16x8*)(&h_lds[mt * 16 + c][s * 32 + g * 8]);
            acc2[mt] = __builtin_amdgcn_mfma_f32_16x16x32_bf16(a, b, acc2[mt], 0, 0, 0);
        }
    }
    float b2v = b2[wave * 16 + c];
#pragma unroll
    for (int mt = 0; mt < 2; mt++)
#pragma unroll
        for (int r = 0; r < 4; r++) {
            int row = node0 + mt * 16 + g * 4 + r;
            if (row < N_NODES) out[(size_t)row * D_OUT + wave * 16 + c] = acc2[mt][r] + b2v;
        }
}

extern "C" void kernel_launch(void* const* d_in, const int* in_sizes, int n_in,
                              void* d_out, int out_size, void* d_ws, size_t ws_size,
                              hipStream_t stream) {
    const float* node_feat = (const float*)d_in[0];
    const float* edge_feat = (const float*)d_in[1];
    const int* senders     = (const int*)d_in[2];
    const int* receivers   = (const int*)d_in[3];
    const float* W1        = (const float*)d_in[4];
    const float* b1        = (const float*)d_in[5];
    const float* W2        = (const float*)d_in[6];
    const float* b2        = (const float*)d_in[7];
    float* out = (float*)d_out;

    // workspace layout
    ushort* x   = (ushort*)d_ws;                       // 50000*128 bf16 = 12.8 MB
    ushort* w1p = x + (size_t)N_NODES * 128;           // 49152 bf16
    ushort* w2p = w1p + 16 * 6 * 64 * 8;               // 16384 bf16
    int* cnt_in   = (int*)(w2p + 4 * 8 * 64 * 8);      // (4-byte aligned: even # ushorts)
    int* cnt_out  = cnt_in + N_NODES;
    int* offs_in  = cnt_out + N_NODES;
    int* offs_out = offs_in + (N_NODES + 1);
    int* cur_in   = offs_out + (N_NODES + 1);
    int* cur_out  = cur_in + (N_NODES + 1);
    int* in_idx   = cur_out + (N_NODES + 1);
    int* out_idx  = in_idx + N_EDGES;

    hipMemsetAsync(cnt_in, 0, (size_t)2 * N_NODES * sizeof(int), stream);

    {
        dim3 grid((N_EDGES + 255) / 256), block(256);
        hist_kernel<<<grid, block, 0, stream>>>(senders, receivers, cnt_in, cnt_out);
    }
    scan_kernel<<<dim3(2), dim3(1024), 0, stream>>>(cnt_in, offs_in, cur_in,
                                                    cnt_out, offs_out, cur_out);
    {
        dim3 grid((N_EDGES + 255) / 256), block(256);
        fill_kernel<<<grid, block, 0, stream>>>(senders, receivers, cur_in, cur_out,
                                                in_idx, out_idx);
    }
    pack_w_kernel<<<dim3(32), dim3(256), 0, stream>>>(W1, W2, w1p, w2p);
    {
        const int tasks = 2 * N_NODES;
        dim3 grid((tasks + 3) / 4), block(256);
        gather_kernel<<<grid, block, 0, stream>>>(edge_feat, offs_in, in_idx,
                                                  offs_out, out_idx, x);
    }
    {
        dim3 grid((N_NODES + 31) / 32), block(256);
        mlp_mfma_kernel<<<grid, block, 0, stream>>>(x, node_feat, w1p, b1, w2p, b2, out);
    }
}